// Round 9
// baseline (518.947 us; speedup 1.0000x reference)
//
#include <hip/hip_runtime.h>
#include <hip/hip_cooperative_groups.h>
#include <math.h>

namespace cg = cooperative_groups;

// ---------------------------------------------------------------------------
// HiPPO-LegS scan via quasiseparable structure of dA (see R6/R7 notes).
// dA = diag(d) + tril(p q^T, -1);  dA c = d*c + p*exclprefix(q*c): O(N)/step.
//
// R6: 3 kernels, NT stores, NCH=16 -> 350 us (passed, absmax 2.4e-4).
// R8: NCH=32 + cached stores -> 393 us. Delta ~= one extra 256MiB HBM trip
//     => cached streaming stores pay RFO; NT is right. VALU budget (~14 us
//     total) says compute never dominated -> 300 us still unexplained and
//     my kernels have never appeared in top-5 (fills 161-173 us mask them).
//
// R9: FUSED single cooperative kernel (1 dispatch -> visible in rocprof with
// its own VALUBusy/WRITE/FETCH), grid.sync() between phases, NT output
// stores, cached scratch. PhaseB: 64 WGs x 1 batch col (4x less serial FMA
// issue than 16-WG version). Scratch lives in d_out slots t=k*CLEN+{0,1}
// and offset 2 of chunks 0..3 (M), each consumed before its owner pass-3
// wave overwrites it.
// ---------------------------------------------------------------------------

#define L_SEQ 4096
#define BATCH 64
#define NST   256
#define NCH   32
#define CLEN  128   // L_SEQ / NCH
#define NBLK  576   // 512 scan-wave blocks + 64 M-column blocks (4 waves/blk)

typedef float fx4 __attribute__((ext_vector_type(4)));  // nontemporal-capable

template<int CTRL, int RMASK>
__device__ __forceinline__ float dpp_mov_f(float x, float ident) {
  union { float f; int i; } a, b, r;
  a.f = x; b.f = ident;
  r.i = __builtin_amdgcn_update_dpp(b.i, a.i, CTRL, RMASK, 0xF, false);
  return r.f;
}

// wave64 inclusive add-scan: row_shr 1,2,4,8 then row_bcast15 (rows 1,3) and
// row_bcast31 (rows 2,3) -- classic GCN DPP scan, ~6 dependent VALU adds.
__device__ __forceinline__ float wave_iscan_add(float v) {
  v += dpp_mov_f<0x111, 0xF>(v, 0.f);
  v += dpp_mov_f<0x112, 0xF>(v, 0.f);
  v += dpp_mov_f<0x114, 0xF>(v, 0.f);
  v += dpp_mov_f<0x118, 0xF>(v, 0.f);
  v += dpp_mov_f<0x142, 0xA>(v, 0.f);
  v += dpp_mov_f<0x143, 0xC>(v, 0.f);
  return v;
}

template<int CTRL, int RMASK>
__device__ __forceinline__ double dpp_mov_d(double x, double ident) {
  union { double d; int i[2]; } a, b, r;
  a.d = x; b.d = ident;
  r.i[0] = __builtin_amdgcn_update_dpp(b.i[0], a.i[0], CTRL, RMASK, 0xF, false);
  r.i[1] = __builtin_amdgcn_update_dpp(b.i[1], a.i[1], CTRL, RMASK, 0xF, false);
  return r.d;
}

__device__ __forceinline__ double wave_iscan_mul(double v) {
  v *= dpp_mov_d<0x111, 0xF>(v, 1.0);
  v *= dpp_mov_d<0x112, 0xF>(v, 1.0);
  v *= dpp_mov_d<0x114, 0xF>(v, 1.0);
  v *= dpp_mov_d<0x118, 0xF>(v, 1.0);
  v *= dpp_mov_d<0x142, 0xA>(v, 1.0);
  v *= dpp_mov_d<0x143, 0xC>(v, 1.0);
  return v;
}

// Per-wave parameter build (fp64, once). Lane l owns n = 4l..4l+3.
__device__ __forceinline__ void compute_params(int lane, const float* __restrict__ dA,
                                               float d[4], float p[4], float q[4]) {
  const double delta = 1.0 / 8192.0;   // dt/2, dt = 1/4096
  double D[4], g[4];
  #pragma unroll
  for (int m = 0; m < 4; ++m) {
    int n = 4 * lane + m;
    D[m] = 1.0 + delta * (double)(n + 1);
    g[m] = 1.0 - delta * (double)(2 * n + 1) / D[m];
  }
  double h01  = g[0] * g[1];
  double h012 = h01 * g[2];
  double h    = h012 * g[3];
  double incl = wave_iscan_mul(h);
  double excl = incl / h;              // W_{4*lane-1}
  double Wm1[4];
  Wm1[0] = excl;
  Wm1[1] = excl * g[0];
  Wm1[2] = excl * h01;
  Wm1[3] = excl * h012;
  #pragma unroll
  for (int m = 0; m < 4; ++m) {
    int n = 4 * lane + m;
    double r = sqrt(2.0 * (double)n + 1.0);
    double W = Wm1[m] * g[m];
    p[m] = (float)(-2.0 * (delta * r / D[m]) * Wm1[m]);
    q[m] = (float)((r / D[m]) / W);
    d[m] = dA[n * NST + n];
  }
}

// One structured recurrence step: c <- d*c + p*exclprefix(q*c) + in
__device__ __forceinline__ void hippo_step(float& c0, float& c1, float& c2, float& c3,
                                           const float d[4], const float p[4], const float q[4],
                                           float i0, float i1, float i2, float i3) {
  float qc0 = q[0] * c0, qc1 = q[1] * c1, qc2 = q[2] * c2, qc3 = q[3] * c3;
  float t01 = qc0 + qc1, t23 = qc2 + qc3, tot = t01 + t23;
  float s  = wave_iscan_add(tot);
  float e0 = s - tot;                 // exclusive over lanes
  float e1 = e0 + qc0, e2 = e0 + t01, e3 = e2 + qc2;
  c0 = fmaf(d[0], c0, fmaf(p[0], e0, i0));
  c1 = fmaf(d[1], c1, fmaf(p[1], e1, i1));
  c2 = fmaf(d[2], c2, fmaf(p[2], e2, i2));
  c3 = fmaf(d[3], c3, fmaf(p[3], e3, i3));
}

__device__ __forceinline__ float bcast_lane(float v, int l) {
  return __int_as_float(__builtin_amdgcn_readlane(__float_as_int(v), l));
}

// scratch slot addresses inside d_out (overwritten later by the owner wave)
__device__ __forceinline__ size_t inc_addr(int k, int b) {
  return ((size_t)(k * CLEN) * BATCH + b) * NST;
}
__device__ __forceinline__ size_t f_addr(int k, int b) {
  return ((size_t)(k * CLEN + 1) * BATCH + b) * NST;
}
__device__ __forceinline__ size_t mt_addr(int j) {
  return ((size_t)((j >> 6) * CLEN + 2) * BATCH + (j & 63)) * NST;
}

__global__ __launch_bounds__(256, 3) void k_fused(const float* __restrict__ u,
                                                  const float* __restrict__ dA,
                                                  const float* __restrict__ dB,
                                                  float* __restrict__ out) {
  cg::grid_group grid = cg::this_grid();
  const int tid  = threadIdx.x;
  const int w    = tid >> 6;
  const int lane = tid & 63;
  const int wid  = blockIdx.x * 4 + w;

  __shared__ float xs[NST];        // phaseB: current x vector (1 KiB)
  __shared__ float red[256 * 5];   // phaseB: partials, stride-5 pad (5 KiB)

  float d[4], p[4], q[4];
  compute_params(lane, dA, d, p, q);

  // ---- phase 1: chunk-local scans (wid < 2048) + M columns (wid >= 2048)
  {
    float c0 = 0.f, c1 = 0.f, c2 = 0.f, c3 = 0.f;
    if (wid < NCH * BATCH) {
      int k = wid >> 6, b = wid & 63;
      float4 db = *reinterpret_cast<const float4*>(dB + 4 * lane);
      for (int half = 0; half < CLEN / 64; ++half) {
        float ur = u[(size_t)(k * CLEN + half * 64 + lane) * BATCH + b];
        #pragma unroll 4
        for (int i = 0; i < 64; ++i) {
          float uv = bcast_lane(ur, i);
          hippo_step(c0, c1, c2, c3, d, p, q,
                     db.x * uv, db.y * uv, db.z * uv, db.w * uv);
        }
      }
      *reinterpret_cast<float4*>(out + f_addr(k, b) + 4 * lane) =
          make_float4(c0, c1, c2, c3);
    } else {
      int j = wid - NCH * BATCH;   // unit column j -> dA^CLEN e_j
      c0 = (4 * lane + 0 == j) ? 1.f : 0.f;
      c1 = (4 * lane + 1 == j) ? 1.f : 0.f;
      c2 = (4 * lane + 2 == j) ? 1.f : 0.f;
      c3 = (4 * lane + 3 == j) ? 1.f : 0.f;
      #pragma unroll 4
      for (int i = 0; i < CLEN; ++i)
        hippo_step(c0, c1, c2, c3, d, p, q, 0.f, 0.f, 0.f, 0.f);
      *reinterpret_cast<float4*>(out + mt_addr(j) + 4 * lane) =
          make_float4(c0, c1, c2, c3);
    }
  }

  grid.sync();

  // ---- phase B: boundary combine, 64 WGs (one batch column each).
  // Wave w owns j-quarter [64w,64w+64); lane l loads M[4l..4l+3][j] as
  // dwordx4 (coalesced column slice); xs[j] is an LDS same-address
  // broadcast. Partials to stride-5-padded LDS (bank = 5*idx%32,
  // gcd(5,32)=1 -> conflict-free); wave 0 finalizes.
  if (blockIdx.x < BATCH) {
    const int b = blockIdx.x;
    xs[tid] = 0.f;
    out[inc_addr(0, b) + tid] = 0.f;    // c_{-1} = 0
    __syncthreads();
    for (int k = 1; k < NCH; ++k) {
      float ax = 0.f, ay = 0.f, az = 0.f, aw = 0.f;
      #pragma unroll 8
      for (int j0 = 0; j0 < 64; ++j0) {
        int j = w * 64 + j0;
        float4 col = *reinterpret_cast<const float4*>(out + mt_addr(j) + 4 * lane);
        float x = xs[j];
        ax = fmaf(col.x, x, ax); ay = fmaf(col.y, x, ay);
        az = fmaf(col.z, x, az); aw = fmaf(col.w, x, aw);
      }
      int idx = (w * 64 + lane) * 5;   // scalar stores: 20 B not 16-B aligned
      red[idx + 0] = ax; red[idx + 1] = ay;
      red[idx + 2] = az; red[idx + 3] = aw;
      __syncthreads();
      if (w == 0) {
        float4 y = *reinterpret_cast<const float4*>(out + f_addr(k - 1, b) + 4 * lane);
        #pragma unroll
        for (int wp = 0; wp < 4; ++wp) {
          int ri = (wp * 64 + lane) * 5;
          y.x += red[ri + 0]; y.y += red[ri + 1];
          y.z += red[ri + 2]; y.w += red[ri + 3];
        }
        *reinterpret_cast<float4*>(out + inc_addr(k, b) + 4 * lane) = y;
        *reinterpret_cast<float4*>(&xs[4 * lane]) = y;   // 16-B aligned
      }
      __syncthreads();
    }
  }

  grid.sync();

  // ---- phase 3: rerun local scans from true incoming states; NT stores
  // (final data, never re-read -- cached stores cost +43us RFO, R8 evidence).
  if (wid < NCH * BATCH) {
    int k = wid >> 6, b = wid & 63;
    float4 db = *reinterpret_cast<const float4*>(dB + 4 * lane);
    size_t oa = inc_addr(k, b) + 4 * lane;
    float4 c = *reinterpret_cast<const float4*>(out + oa);  // read-then-overwrite
    float c0 = c.x, c1 = c.y, c2 = c.z, c3 = c.w;
    for (int half = 0; half < CLEN / 64; ++half) {
      float ur = u[(size_t)(k * CLEN + half * 64 + lane) * BATCH + b];
      #pragma unroll 4
      for (int i = 0; i < 64; ++i) {
        float uv = bcast_lane(ur, i);
        hippo_step(c0, c1, c2, c3, d, p, q,
                   db.x * uv, db.y * uv, db.z * uv, db.w * uv);
        fx4 v; v.x = c0; v.y = c1; v.z = c2; v.w = c3;
        __builtin_nontemporal_store(v, reinterpret_cast<fx4*>(out + oa));
        oa += (size_t)BATCH * NST;   // next t
      }
    }
  }
}

extern "C" void kernel_launch(void* const* d_in, const int* in_sizes, int n_in,
                              void* d_out, int out_size, void* d_ws, size_t ws_size,
                              hipStream_t stream) {
  const float* u  = (const float*)d_in[0];
  const float* dA = (const float*)d_in[1];
  const float* dB = (const float*)d_in[2];
  float* out = (float*)d_out;
  (void)in_sizes; (void)n_in; (void)out_size; (void)d_ws; (void)ws_size;

  void* args[] = {(void*)&u, (void*)&dA, (void*)&dB, (void*)&out};
  hipLaunchCooperativeKernel((const void*)k_fused, dim3(NBLK), dim3(256),
                             args, 0, stream);
}